// Round 1
// baseline (56.166 us; speedup 1.0000x reference)
//
#include <hip/hip_runtime.h>

#define N 8
#define NANGS 28
#define COLS 512
#define QUADS (COLS / 4)   // 128 float4 column-groups per row

// One HIP block per transform block b. 128 threads: thread t owns float4
// column-group q=t. Threads 0..7 cooperatively build R (each owns one column
// of the 8x8 matrix across the serial 28-step Givens chain).
__global__ __launch_bounds__(128) void sot_kernel(
    const float* __restrict__ X,
    const float* __restrict__ angles,
    const float* __restrict__ mus,
    float* __restrict__ Y)
{
    const int b = blockIdx.x;
    const int t = threadIdx.x;

    __shared__ float Rs[N][N];

    // ---- Prefetch X before the barrier so HBM latency overlaps R build ----
    const float4* __restrict__ Xb = (const float4*)(X + (size_t)b * N * COLS);
    float4* __restrict__ Yb = (float4*)(Y + (size_t)b * N * COLS);

    float4 xv[N];
#pragma unroll
    for (int j = 0; j < N; ++j) {
        xv[j] = Xb[j * QUADS + t];   // lanes read consecutive float4: coalesced
    }

    // ---- Build R: threads 0..7, thread k owns column k ----
    if (t < N) {
        const int k = t;
        float m[N];
#pragma unroll
        for (int i = 0; i < N; ++i) m[i] = (i == k) ? 1.0f : 0.0f;

        const float* __restrict__ ang = angles + (size_t)b * NANGS;
        int p = 0;
#pragma unroll
        for (int iTop = 0; iTop < N; ++iTop) {
#pragma unroll
            for (int iBtm = iTop + 1; iBtm < N; ++iBtm) {
                const float a = ang[p++];
                const float c = cosf(a);
                const float s = sinf(a);
                const float vt = m[iTop];
                const float vb = m[iBtm];
                m[iTop] = c * vt - s * vb;
                m[iBtm] = s * vt + c * vb;
            }
        }
        const float* __restrict__ mu = mus + (size_t)b * N;
#pragma unroll
        for (int i = 0; i < N; ++i) Rs[i][k] = mu[i] * m[i];
    }
    __syncthreads();

    // ---- Y[i][q] = sum_j R[i][j] * X[j][q] ----
#pragma unroll
    for (int i = 0; i < N; ++i) {
        float4 acc = make_float4(0.f, 0.f, 0.f, 0.f);
#pragma unroll
        for (int j = 0; j < N; ++j) {
            const float r = Rs[i][j];   // wave-uniform LDS read: broadcast, free
            acc.x += r * xv[j].x;
            acc.y += r * xv[j].y;
            acc.z += r * xv[j].z;
            acc.w += r * xv[j].w;
        }
        Yb[i * QUADS + t] = acc;        // coalesced float4 store
    }
}

extern "C" void kernel_launch(void* const* d_in, const int* in_sizes, int n_in,
                              void* d_out, int out_size, void* d_ws, size_t ws_size,
                              hipStream_t stream)
{
    const float* X      = (const float*)d_in[0];
    const float* angles = (const float*)d_in[1];
    const float* mus    = (const float*)d_in[2];
    float* Y = (float*)d_out;

    const int nblks = in_sizes[1] / NANGS;   // 8192

    sot_kernel<<<nblks, 128, 0, stream>>>(X, angles, mus, Y);
}

// Round 2
// 45.082 us; speedup vs baseline: 1.2459x; 1.2459x over previous
//
#include <hip/hip_runtime.h>

#define N 8
#define NANGS 28
#define COLS 512
#define QUADS (COLS / 4)   // 128 float4 column-groups per row

// One HIP block per transform block b. 128 threads: thread t owns float4
// column-group q=t.
// Phase 0: everyone issues X loads (latency overlaps R build).
//          threads 0..27 compute sincos of their angle -> LDS (parallel trig).
// Phase 1: threads 0..7 run the 28-step Givens chain (pure FMAs from LDS c/s).
// Phase 2: 8x8 multiply, coalesced float4 stores.
__global__ __launch_bounds__(128) void sot_kernel(
    const float* __restrict__ X,
    const float* __restrict__ angles,
    const float* __restrict__ mus,
    float* __restrict__ Y)
{
    const int b = blockIdx.x;
    const int t = threadIdx.x;

    __shared__ float Rs[N][N];
    __shared__ float Cs[NANGS];
    __shared__ float Ss[NANGS];
    __shared__ float Ms[N];

    // ---- Critical-path loads first: angles + mus ----
    float a = 0.0f;
    if (t < NANGS) a = angles[(size_t)b * NANGS + t];
    if (t < N)     Ms[t] = mus[(size_t)b * N + t];

    // ---- Prefetch X so HBM latency overlaps the R build ----
    const float4* __restrict__ Xb = (const float4*)(X + (size_t)b * N * COLS);
    float4* __restrict__ Yb = (float4*)(Y + (size_t)b * N * COLS);

    float4 xv[N];
#pragma unroll
    for (int j = 0; j < N; ++j) {
        xv[j] = Xb[j * QUADS + t];   // lanes read consecutive float4: coalesced
    }

    // ---- Parallel trig: thread p computes (cos,sin) of angle p ----
    if (t < NANGS) {
        float s, c;
        __sincosf(a, &s, &c);        // hardware v_sin/v_cos path
        Cs[t] = c;
        Ss[t] = s;
    }
    __syncthreads();

    // ---- Short serial chain: thread k owns column k of R ----
    if (t < N) {
        const int k = t;
        float m[N];
#pragma unroll
        for (int i = 0; i < N; ++i) m[i] = (i == k) ? 1.0f : 0.0f;

        int p = 0;
#pragma unroll
        for (int iTop = 0; iTop < N; ++iTop) {
#pragma unroll
            for (int iBtm = iTop + 1; iBtm < N; ++iBtm) {
                const float c = Cs[p];
                const float s = Ss[p];
                ++p;
                const float vt = m[iTop];
                const float vb = m[iBtm];
                m[iTop] = c * vt - s * vb;
                m[iBtm] = s * vt + c * vb;
            }
        }
#pragma unroll
        for (int i = 0; i < N; ++i) Rs[i][k] = Ms[i] * m[i];
    }
    __syncthreads();

    // ---- Y[i][q] = sum_j R[i][j] * X[j][q] ----
#pragma unroll
    for (int i = 0; i < N; ++i) {
        float4 acc = make_float4(0.f, 0.f, 0.f, 0.f);
#pragma unroll
        for (int j = 0; j < N; ++j) {
            const float r = Rs[i][j];   // wave-uniform LDS read: broadcast
            acc.x += r * xv[j].x;
            acc.y += r * xv[j].y;
            acc.z += r * xv[j].z;
            acc.w += r * xv[j].w;
        }
        Yb[i * QUADS + t] = acc;        // coalesced float4 store
    }
}

extern "C" void kernel_launch(void* const* d_in, const int* in_sizes, int n_in,
                              void* d_out, int out_size, void* d_ws, size_t ws_size,
                              hipStream_t stream)
{
    const float* X      = (const float*)d_in[0];
    const float* angles = (const float*)d_in[1];
    const float* mus    = (const float*)d_in[2];
    float* Y = (float*)d_out;

    const int nblks = in_sizes[1] / NANGS;   // 8192

    sot_kernel<<<nblks, 128, 0, stream>>>(X, angles, mus, Y);
}

// Round 4
// 44.466 us; speedup vs baseline: 1.2631x; 1.0138x over previous
//
#include <hip/hip_runtime.h>

#define N 8
#define NANGS 28
#define COLS 512
#define QUADS (COLS / 4)   // 128 float4 column-groups per row

typedef float f32x4 __attribute__((ext_vector_type(4)));   // native vec for nt store

// One HIP block per transform block b; thread t owns float4 column-group q=t.
// Barrier-free: each thread holds its 8 float4 (one per row) in registers and
// applies the 28 Givens rotations DIRECTLY to them (Y = G28(...(G1 X)), then
// row scaling by mus) — no R matrix, no LDS, no __syncthreads.
// Y is streamed out with nontemporal stores (write-once data; keeps X in L3).
__global__ __launch_bounds__(128) void sot_kernel(
    const float* __restrict__ X,
    const float* __restrict__ angles,
    const float* __restrict__ mus,
    float* __restrict__ Y)
{
    const int b = blockIdx.x;
    const int t = threadIdx.x;

    const f32x4* __restrict__ Xb = (const f32x4*)(X + (size_t)b * N * COLS);
    f32x4*       __restrict__ Yb = (f32x4*)(Y + (size_t)b * N * COLS);
    const float* __restrict__ ang = angles + (size_t)b * NANGS;
    const float* __restrict__ mu  = mus + (size_t)b * N;

    // Coalesced row loads: lanes read consecutive float4 (1 KiB / wave instr).
    f32x4 xv[N];
#pragma unroll
    for (int j = 0; j < N; ++j) xv[j] = Xb[j * QUADS + t];

    // Apply the rotation chain in reference order (iTop asc, iBtm asc).
    int p = 0;
#pragma unroll
    for (int iTop = 0; iTop < N; ++iTop) {
#pragma unroll
        for (int iBtm = iTop + 1; iBtm < N; ++iBtm) {
            const float a = ang[p++];
            float ss, cc;
            __sincosf(a, &ss, &cc);   // hardware v_sin/v_cos path
            const f32x4 vt = xv[iTop];
            const f32x4 vb = xv[iBtm];
            xv[iTop] = cc * vt - ss * vb;
            xv[iBtm] = ss * vt + cc * vb;
        }
    }

    // Row sign/scale + nontemporal coalesced stores.
#pragma unroll
    for (int i = 0; i < N; ++i) {
        const f32x4 v = xv[i] * mu[i];
        __builtin_nontemporal_store(v, &Yb[i * QUADS + t]);
    }
}

extern "C" void kernel_launch(void* const* d_in, const int* in_sizes, int n_in,
                              void* d_out, int out_size, void* d_ws, size_t ws_size,
                              hipStream_t stream)
{
    const float* X      = (const float*)d_in[0];
    const float* angles = (const float*)d_in[1];
    const float* mus    = (const float*)d_in[2];
    float* Y = (float*)d_out;

    const int nblks = in_sizes[1] / NANGS;   // 8192

    sot_kernel<<<nblks, 128, 0, stream>>>(X, angles, mus, Y);
}

// Round 6
// 44.416 us; speedup vs baseline: 1.2646x; 1.0011x over previous
//
#include <hip/hip_runtime.h>

#define N 8
#define NANGS 28
#define COLS 512
#define QUADS (COLS / 4)   // 128 float4 column-groups per row

typedef float f32x4 __attribute__((ext_vector_type(4)));

// One HIP block per transform block b; thread t owns float4 column-group q=t.
// Barrier-free: each thread holds its 8 float4 (one per row) in registers and
// applies the 28 Givens rotations directly (Y = G28(...(G1 X)), then row
// scaling by mus) — no R matrix, no LDS, no __syncthreads.
// Y stores: single asm block with sc0+sc1+nt cache bits (no L2/L3 allocate)
// + trailing s_waitcnt vmcnt(0) so the compiler can't reuse data VGPRs and
// the wave can't end with stores in flight (the R5 corruption bug).
__global__ __launch_bounds__(128) void sot_kernel(
    const float* __restrict__ X,
    const float* __restrict__ angles,
    const float* __restrict__ mus,
    float* __restrict__ Y)
{
    const int b = blockIdx.x;
    const int t = threadIdx.x;

    const f32x4* __restrict__ Xb = (const f32x4*)(X + (size_t)b * N * COLS);
    f32x4*       __restrict__ Yb = (f32x4*)(Y + (size_t)b * N * COLS);
    const float* __restrict__ ang = angles + (size_t)b * NANGS;
    const float* __restrict__ mu  = mus + (size_t)b * N;

    // Coalesced row loads: lanes read consecutive float4 (1 KiB / wave instr).
    f32x4 xv[N];
#pragma unroll
    for (int j = 0; j < N; ++j) xv[j] = Xb[j * QUADS + t];

    // Apply the rotation chain in reference order (iTop asc, iBtm asc).
    int p = 0;
#pragma unroll
    for (int iTop = 0; iTop < N; ++iTop) {
#pragma unroll
        for (int iBtm = iTop + 1; iBtm < N; ++iBtm) {
            const float a = ang[p++];
            float ss, cc;
            __sincosf(a, &ss, &cc);   // hardware v_sin/v_cos path
            const f32x4 vt = xv[iTop];
            const f32x4 vb = xv[iBtm];
            xv[iTop] = cc * vt - ss * vb;
            xv[iBtm] = ss * vt + cc * vb;
        }
    }

    // Row sign/scale.
    f32x4 v0 = xv[0] * mu[0];
    f32x4 v1 = xv[1] * mu[1];
    f32x4 v2 = xv[2] * mu[2];
    f32x4 v3 = xv[3] * mu[3];
    f32x4 v4 = xv[4] * mu[4];
    f32x4 v5 = xv[5] * mu[5];
    f32x4 v6 = xv[6] * mu[6];
    f32x4 v7 = xv[7] * mu[7];

    f32x4* a0 = &Yb[0 * QUADS + t];
    f32x4* a1 = &Yb[1 * QUADS + t];
    f32x4* a2 = &Yb[2 * QUADS + t];
    f32x4* a3 = &Yb[3 * QUADS + t];
    f32x4* a4 = &Yb[4 * QUADS + t];
    f32x4* a5 = &Yb[5 * QUADS + t];
    f32x4* a6 = &Yb[6 * QUADS + t];
    f32x4* a7 = &Yb[7 * QUADS + t];

    // All stores in ONE asm block: every data/addr VGPR stays live until the
    // final vmcnt(0), so no reuse-while-in-flight and no endpgm hazard.
    asm volatile(
        "global_store_dwordx4 %8,  %0, off sc0 sc1 nt\n\t"
        "global_store_dwordx4 %9,  %1, off sc0 sc1 nt\n\t"
        "global_store_dwordx4 %10, %2, off sc0 sc1 nt\n\t"
        "global_store_dwordx4 %11, %3, off sc0 sc1 nt\n\t"
        "global_store_dwordx4 %12, %4, off sc0 sc1 nt\n\t"
        "global_store_dwordx4 %13, %5, off sc0 sc1 nt\n\t"
        "global_store_dwordx4 %14, %6, off sc0 sc1 nt\n\t"
        "global_store_dwordx4 %15, %7, off sc0 sc1 nt\n\t"
        "s_waitcnt vmcnt(0)"
        :: "v"(v0), "v"(v1), "v"(v2), "v"(v3),
           "v"(v4), "v"(v5), "v"(v6), "v"(v7),
           "v"(a0), "v"(a1), "v"(a2), "v"(a3),
           "v"(a4), "v"(a5), "v"(a6), "v"(a7)
        : "memory");
}

extern "C" void kernel_launch(void* const* d_in, const int* in_sizes, int n_in,
                              void* d_out, int out_size, void* d_ws, size_t ws_size,
                              hipStream_t stream)
{
    const float* X      = (const float*)d_in[0];
    const float* angles = (const float*)d_in[1];
    const float* mus    = (const float*)d_in[2];
    float* Y = (float*)d_out;

    const int nblks = in_sizes[1] / NANGS;   // 8192

    sot_kernel<<<nblks, 128, 0, stream>>>(X, angles, mus, Y);
}